// Round 12
// baseline (178.564 us; speedup 1.0000x reference)
//
#include <hip/hip_runtime.h>
#include <hip/hip_bf16.h>
#include <hip/hip_fp8.h>
#include <cstddef>
#include <cstdint>

typedef __attribute__((ext_vector_type(8))) short short8;
typedef __attribute__((ext_vector_type(4))) float f32x4;
typedef __attribute__((ext_vector_type(2))) float f32x2;

static constexpr int F_IN  = 512;
static constexpr int F_H   = 128;
static constexpr int F_OUT = 40;
static constexpr int F_OP  = 48;
static constexpr int H2B   = 48;

__device__ inline unsigned short f2bf(float f) {
  return __builtin_bit_cast(unsigned short, __float2bfloat16(f));
}
__device__ inline float bf2f(uint32_t lo16) {
  return __builtin_bit_cast(float, lo16 << 16);
}
__device__ inline void gload_lds16(const void* g, void* l) {
  __builtin_amdgcn_global_load_lds(
      (const __attribute__((address_space(1))) void*)g,
      (__attribute__((address_space(3))) void*)l, 16, 0, 0);
}

// ---------------- fp8 e4m3 (OCP on gfx950) helpers ----------------
#if __has_builtin(__builtin_amdgcn_cvt_pk_fp8_f32) && __has_builtin(__builtin_amdgcn_cvt_pk_f32_fp8)
#define FP8_HW 1
#else
#define FP8_HW 0
#endif

__device__ inline uint32_t f2fp8x2(float a, float b) {
#if FP8_HW
  return (uint32_t)__builtin_amdgcn_cvt_pk_fp8_f32(a, b, 0, false) & 0xFFFFu;
#else
  __hip_fp8_e4m3 ta(a), tb(b);
  return (uint32_t)ta.__x | ((uint32_t)tb.__x << 8);
#endif
}

__device__ inline void fp8x8_to_f32(uint2 u, float* o) {
#if FP8_HW
  f32x2 p0 = __builtin_amdgcn_cvt_pk_f32_fp8(u.x, false);
  f32x2 p1 = __builtin_amdgcn_cvt_pk_f32_fp8(u.x, true);
  f32x2 p2 = __builtin_amdgcn_cvt_pk_f32_fp8(u.y, false);
  f32x2 p3 = __builtin_amdgcn_cvt_pk_f32_fp8(u.y, true);
  o[0] = p0[0]; o[1] = p0[1]; o[2] = p1[0]; o[3] = p1[1];
  o[4] = p2[0]; o[5] = p2[1]; o[6] = p3[0]; o[7] = p3[1];
#else
  uint32_t w[2] = {u.x, u.y};
#pragma unroll
  for (int i = 0; i < 8; ++i) {
    __hip_fp8_e4m3 t; t.__x = (uint8_t)((w[i >> 2] >> ((i & 3) * 8)) & 0xFF);
    o[i] = (float)t;
  }
#endif
}

// ---------------- K1: zero cnt + convert W1/W2 ----------------
__global__ void k_init(const float* __restrict__ W1, const float* __restrict__ W2,
                       unsigned short* __restrict__ W1t, unsigned short* __restrict__ W2t,
                       int* __restrict__ cnt, int N) {
  int i = blockIdx.x * blockDim.x + threadIdx.x;
  if (i < F_H * F_IN) {
    int f = i >> 9, k = i & 511;
    W1t[i] = f2bf(W1[(size_t)k * F_H + f]);
  } else {
    int j = i - F_H * F_IN;
    if (j < F_OP * F_H) {
      int c = j >> 7, k = j & 127;
      float v = (c < F_OUT) ? W2[(size_t)k * F_OUT + c] : 0.f;
      W2t[j] = f2bf(v);
    }
  }
  if (i < N) cnt[i] = 0;
}

// ---------------- K2: degree count ----------------
__global__ void k_count(const int* __restrict__ dst, int* __restrict__ cnt, int E) {
  int e = blockIdx.x * blockDim.x + threadIdx.x;
  if (e < E) atomicAdd(&cnt[dst[e]], 1);
}

// ---------------- K3: per-block scan ----------------
__global__ void k_scan_local(const int* __restrict__ cnt, int* __restrict__ rp,
                             int* __restrict__ bsum, int N) {
  __shared__ int tmp[1024];
  int t = threadIdx.x;
  int i = blockIdx.x * 1024 + t;
  int v = (i < N) ? cnt[i] : 0;
  tmp[t] = v;
  __syncthreads();
  for (int off = 1; off < 1024; off <<= 1) {
    int u = (t >= off) ? tmp[t - off] : 0;
    __syncthreads();
    tmp[t] += u;
    __syncthreads();
  }
  if (i < N) rp[i] = tmp[t] - v;
  if (t == 1023) bsum[blockIdx.x] = tmp[1023];
}

// ---------------- K4: finalize row_ptr, seed cursor, dinv ----------------
__global__ void k_scan_add(int* __restrict__ rp, const int* __restrict__ bsum,
                           const int* __restrict__ cnt, int* __restrict__ cursor,
                           float* __restrict__ dinv, int N, int E, int nb) {
  __shared__ int sb[64];
  int t = threadIdx.x;
  if (t < 64) {
    int v = (t < nb) ? bsum[t] : 0;
    int orig = v;
#pragma unroll
    for (int off = 1; off < 64; off <<= 1) {
      int u = __shfl_up(v, off);
      if ((t & 63) >= off) v += u;
    }
    sb[t] = v - orig;
  }
  __syncthreads();
  int i = blockIdx.x * blockDim.x + t;
  if (i < N) {
    int r = rp[i] + sb[i >> 10];
    rp[i] = r;
    cursor[i] = r;
    dinv[i] = rsqrtf((float)cnt[i] + 1.0f);
  }
  if (i == N) rp[N] = E;
}

// ---------------- K5: scatter (lean: no LDS, full occupancy) ---------------
__global__ void k_scatter(const int* __restrict__ src, const int* __restrict__ dst,
                          int* __restrict__ cursor, int* __restrict__ src_sorted, int E) {
  int e = blockIdx.x * blockDim.x + threadIdx.x;
  if (e >= E) return;
  int d = dst[e];
  int pos = atomicAdd(&cursor[d], 1);
  src_sorted[pos] = src[e];
}

// ---------------- K6: GEMM1 (MFMA bf16), A-prefetch pipelined --------------
// BM=64, BN=128, BK=64. A: direct-from-global, prefetched one K-tile ahead
// into registers (latency hides under MFMA block). B: global_load_lds into
// XOR-swizzled double-buffered LDS. Output h1 fp8 [N][128].
__global__ __launch_bounds__(256) void k_gemm1(const float* __restrict__ x,
                                               const unsigned short* __restrict__ Wt,
                                               unsigned char* __restrict__ h, int N) {
  __shared__ unsigned short Bt[2][128][64];   // 32 KB
  const int t = threadIdx.x, lane = t & 63, w = t >> 6;
  const int l16 = lane & 15, g = lane >> 4;
  const int row0 = blockIdx.x * 64;

  int bsrow[4], bslc[4];
#pragma unroll
  for (int r = 0; r < 4; ++r) {
    int rg = r * 32 + w * 8;
    bsrow[r] = rg + (lane >> 3);
    bslc[r]  = (lane & 7) ^ (bsrow[r] & 7);
  }

  int ar = row0 + w * 16 + l16; if (ar >= N) ar = N - 1;
  const float* ap = x + (size_t)ar * F_IN + g * 8;

  f32x4 acc[8];
#pragma unroll
  for (int j = 0; j < 8; ++j) acc[j] = (f32x4){0.f, 0.f, 0.f, 0.f};

  auto issueB = [&](int buf, int k0) {
#pragma unroll
    for (int r = 0; r < 4; ++r)
      gload_lds16(Wt + (size_t)bsrow[r] * F_IN + k0 + bslc[r] * 8,
                  &Bt[buf][r * 32 + w * 8][0]);
  };

  auto loadA = [&](int kt, float4* d) {
    const float* p = ap + kt * 64;
    d[0] = *(const float4*)(p);
    d[1] = *(const float4*)(p + 4);
    d[2] = *(const float4*)(p + 32);
    d[3] = *(const float4*)(p + 36);
  };

  float4 avc[4], avn[4];
  loadA(0, avc);
  issueB(0, 0);
  __syncthreads();

  for (int kt = 0; kt < 8; ++kt) {
    const int cur = kt & 1;
    if (kt < 7) {
      issueB(cur ^ 1, (kt + 1) * 64);
      loadA(kt + 1, avn);          // issue-early: hides under MFMA below
    }

    short8 af[2];
#pragma unroll
    for (int ks = 0; ks < 2; ++ks) {
      float4 lo = avc[ks * 2], hi = avc[ks * 2 + 1];
      short8 v;
      v[0] = (short)f2bf(lo.x); v[1] = (short)f2bf(lo.y);
      v[2] = (short)f2bf(lo.z); v[3] = (short)f2bf(lo.w);
      v[4] = (short)f2bf(hi.x); v[5] = (short)f2bf(hi.y);
      v[6] = (short)f2bf(hi.z); v[7] = (short)f2bf(hi.w);
      af[ks] = v;
    }

#pragma unroll
    for (int ks = 0; ks < 2; ++ks) {
      const int lcf = ks * 4 + g;
      short8 bfr[8];
#pragma unroll
      for (int fc = 0; fc < 8; ++fc) {
        int rr = fc * 16 + l16;
        bfr[fc] = *(const short8*)&Bt[cur][rr][(lcf ^ (rr & 7)) * 8];
      }
#pragma unroll
      for (int fc = 0; fc < 8; ++fc)
        acc[fc] = __builtin_amdgcn_mfma_f32_16x16x32_bf16(af[ks], bfr[fc], acc[fc], 0, 0, 0);
    }

#pragma unroll
    for (int q = 0; q < 4; ++q) avc[q] = avn[q];
    __syncthreads();
  }

  int rbase = row0 + w * 16 + g * 4;
#pragma unroll
  for (int fc = 0; fc < 8; ++fc) {
    int col = fc * 16 + l16;
#pragma unroll
    for (int jp = 0; jp < 2; ++jp) {
      uint32_t pk = f2fp8x2(acc[fc][jp * 2], acc[fc][jp * 2 + 1]);
      int r0 = rbase + jp * 2;
      if (r0 < N)     h[(size_t)r0 * F_H + col]       = (unsigned char)(pk & 0xFF);
      if (r0 + 1 < N) h[(size_t)(r0 + 1) * F_H + col] = (unsigned char)(pk >> 8);
    }
  }
}

// ---------------- K7: lean agg1 (fp8 gather -> bf16 a1, +bias+ReLU) --------
__global__ void k_agg1(const unsigned char* __restrict__ h, const float* __restrict__ dinv,
                       const int* __restrict__ rp, const int* __restrict__ srcs,
                       const float* __restrict__ bias, unsigned short* __restrict__ out, int N) {
  int gid = blockIdx.x * blockDim.x + threadIdx.x;
  int n = gid >> 4;
  if (n >= N) return;
  const int lane = threadIdx.x & 63;
  const int l16 = lane & 15;
  const int gbase = lane & 48;
  const int f = l16 * 8;

  float dn = dinv[n];
  float acc[8], tmp[8];
  uint2 sv = *(const uint2*)(h + (size_t)n * F_H + f);
  fp8x8_to_f32(sv, tmp);
  float sl = dn * dn;
#pragma unroll
  for (int i = 0; i < 8; ++i) acc[i] = tmp[i] * sl;

  int beg = rp[n], end = rp[n + 1];
  for (int jb = beg; jb < end; jb += 16) {
    int lim = end - jb; if (lim > 16) lim = 16;
    int sidx = srcs[jb + ((l16 < lim) ? l16 : 0)];
    float sdv = dinv[sidx];

    if (lim == 16) {
#pragma unroll
      for (int i = 0; i < 16; ++i) {
        int s = __shfl(sidx, gbase + i);
        float nr = __shfl(sdv, gbase + i) * dn;
        uint2 hv = *(const uint2*)(h + (size_t)s * F_H + f);
        fp8x8_to_f32(hv, tmp);
#pragma unroll
        for (int q = 0; q < 8; ++q) acc[q] += tmp[q] * nr;
      }
    } else {
      for (int i = 0; i < lim; ++i) {
        int s = __shfl(sidx, gbase + i);
        float nr = __shfl(sdv, gbase + i) * dn;
        uint2 hv = *(const uint2*)(h + (size_t)s * F_H + f);
        fp8x8_to_f32(hv, tmp);
#pragma unroll
        for (int q = 0; q < 8; ++q) acc[q] += tmp[q] * nr;
      }
    }
  }

#pragma unroll
  for (int i = 0; i < 8; ++i) {
    acc[i] += bias[f + i];
    acc[i] = fmaxf(acc[i], 0.f);
  }
  uint4 o;
  o.x = f2bf(acc[0]) | ((unsigned)f2bf(acc[1]) << 16);
  o.y = f2bf(acc[2]) | ((unsigned)f2bf(acc[3]) << 16);
  o.z = f2bf(acc[4]) | ((unsigned)f2bf(acc[5]) << 16);
  o.w = f2bf(acc[6]) | ((unsigned)f2bf(acc[7]) << 16);
  *(uint4*)(out + (size_t)n * F_H + f) = o;
}

// ---------------- K8: GEMM2 (MFMA bf16): h2 = a1 @ W2 -> fp8 [N][48B] ------
__global__ __launch_bounds__(256) void k_gemm2(const unsigned short* __restrict__ a,
                                               const unsigned short* __restrict__ W2t,
                                               unsigned char* __restrict__ h2, int N) {
  const int t = threadIdx.x, lane = t & 63, w = t >> 6;
  const int l16 = lane & 15, g = lane >> 4;
  const int row0 = blockIdx.x * 128 + w * 32;

  short8 bfr[3][4];
#pragma unroll
  for (int fc = 0; fc < 3; ++fc)
#pragma unroll
    for (int ks = 0; ks < 4; ++ks)
      bfr[fc][ks] = *(const short8*)(W2t + (size_t)(fc * 16 + l16) * F_H + ks * 32 + g * 8);

  f32x4 acc[2][3];
#pragma unroll
  for (int i = 0; i < 2; ++i)
#pragma unroll
    for (int j = 0; j < 3; ++j) acc[i][j] = (f32x4){0.f, 0.f, 0.f, 0.f};

  short8 af[2][4];
#pragma unroll
  for (int fr = 0; fr < 2; ++fr) {
    int r = row0 + fr * 16 + l16; if (r >= N) r = N - 1;
#pragma unroll
    for (int ks = 0; ks < 4; ++ks)
      af[fr][ks] = *(const short8*)(a + (size_t)r * F_H + ks * 32 + g * 8);
  }

#pragma unroll
  for (int fr = 0; fr < 2; ++fr)
#pragma unroll
    for (int ks = 0; ks < 4; ++ks)
#pragma unroll
      for (int fc = 0; fc < 3; ++fc)
        acc[fr][fc] = __builtin_amdgcn_mfma_f32_16x16x32_bf16(af[fr][ks], bfr[fc][ks], acc[fr][fc], 0, 0, 0);

#pragma unroll
  for (int fr = 0; fr < 2; ++fr) {
    int rbase = row0 + fr * 16 + g * 4;
#pragma unroll
    for (int fc = 0; fc < 3; ++fc) {
      int col = fc * 16 + l16;
#pragma unroll
      for (int jp = 0; jp < 2; ++jp) {
        uint32_t pk = f2fp8x2(acc[fr][fc][jp * 2], acc[fr][fc][jp * 2 + 1]);
        int r0 = rbase + jp * 2;
        if (r0 < N)     h2[(size_t)r0 * H2B + col]       = (unsigned char)(pk & 0xFF);
        if (r0 + 1 < N) h2[(size_t)(r0 + 1) * H2B + col] = (unsigned char)(pk >> 8);
      }
    }
  }
}

// ---------------- K9: layer-2 agg + b2 + log_softmax -----------------------
__global__ void k_agg2sm(const unsigned char* __restrict__ h2, const float* __restrict__ dinv,
                         const int* __restrict__ rp, const int* __restrict__ srcs,
                         const float* __restrict__ b2, float* __restrict__ out, int N) {
  int gid = blockIdx.x * blockDim.x + threadIdx.x;
  int n = gid >> 3;
  if (n >= N) return;
  const int lane = threadIdx.x & 63;
  const int l8 = lane & 7;
  const int gb = lane & 56;
  const int f = l8 * 8;
  const bool live = (l8 < 5);

  float dn = dinv[n];
  float acc[8], tmp[8];
#pragma unroll
  for (int i = 0; i < 8; ++i) acc[i] = 0.f;
  if (live) {
    uint2 sv = *(const uint2*)(h2 + (size_t)n * H2B + f);
    fp8x8_to_f32(sv, tmp);
    float sl = dn * dn;
#pragma unroll
    for (int i = 0; i < 8; ++i) acc[i] = tmp[i] * sl;
  }

  int beg = rp[n], end = rp[n + 1];
  for (int jb = beg; jb < end; jb += 8) {
    int lim = end - jb; if (lim > 8) lim = 8;
    int sidx = srcs[jb + ((l8 < lim) ? l8 : 0)];
    float sdv = dinv[sidx];

    for (int i = 0; i < lim; ++i) {
      int s = __shfl(sidx, gb + i);
      float nr = __shfl(sdv, gb + i) * dn;
      if (live) {
        uint2 hv = *(const uint2*)(h2 + (size_t)s * H2B + f);
        fp8x8_to_f32(hv, tmp);
#pragma unroll
        for (int q = 0; q < 8; ++q) acc[q] += tmp[q] * nr;
      }
    }
  }

  float vals[8];
  float m = -3.0e38f;
#pragma unroll
  for (int q = 0; q < 8; ++q) {
    int col = f + q;
    if (col < F_OUT) {
      vals[q] = acc[q] + b2[col];
      m = fmaxf(m, vals[q]);
    } else {
      vals[q] = -3.0e38f;
    }
  }
#pragma unroll
  for (int off = 4; off > 0; off >>= 1) m = fmaxf(m, __shfl_xor(m, off));
  float e = 0.f;
#pragma unroll
  for (int q = 0; q < 8; ++q) {
    int col = f + q;
    if (col < F_OUT) e += expf(vals[q] - m);
  }
#pragma unroll
  for (int off = 4; off > 0; off >>= 1) e += __shfl_xor(e, off);
  float ls = logf(e) + m;

  if (live) {
    float4 o0 = {vals[0] - ls, vals[1] - ls, vals[2] - ls, vals[3] - ls};
    float4 o1 = {vals[4] - ls, vals[5] - ls, vals[6] - ls, vals[7] - ls};
    float* op = out + (size_t)n * F_OUT + f;
    *(float4*)op = o0;
    *(float4*)(op + 4) = o1;
  }
}

extern "C" void kernel_launch(void* const* d_in, const int* in_sizes, int n_in,
                              void* d_out, int out_size, void* d_ws, size_t ws_size,
                              hipStream_t stream) {
  const float* x  = (const float*)d_in[0];
  const int*   ei = (const int*)d_in[1];
  const float* W1 = (const float*)d_in[2];
  const float* b1 = (const float*)d_in[3];
  const float* W2 = (const float*)d_in[4];
  const float* b2 = (const float*)d_in[5];

  const int N = in_sizes[0] / F_IN;   // 50000
  const int E = in_sizes[1] / 2;      // 800000
  const int* src = ei;
  const int* dst = ei + E;

  // workspace layout (byte-addressed, 256B-aligned chunks)
  char* base = (char*)d_ws;
  auto alloc = [&](size_t bytes) {
    char* p = base;
    base += (bytes + 255) & ~(size_t)255;
    return p;
  };
  size_t Npad = ((size_t)N + 1023) & ~(size_t)1023;
  float*          dinv    = (float*)alloc(Npad * 4);
  unsigned char*  h1      = (unsigned char*)alloc((size_t)N * F_H);        // fp8
  unsigned short* a1b     = (unsigned short*)alloc((size_t)N * F_H * 2);   // bf16
  unsigned char*  h2      = (unsigned char*)alloc((size_t)N * H2B);        // fp8
  int*            cnt     = (int*)alloc(Npad * 4);
  int*            row_ptr = (int*)alloc((Npad + 64) * 4);
  int*            cursor  = (int*)alloc(Npad * 4);
  int*            src_sorted = (int*)alloc((size_t)E * 4);
  unsigned short* W1t     = (unsigned short*)alloc((size_t)F_H * F_IN * 2);
  unsigned short* W2t     = (unsigned short*)alloc((size_t)F_OP * F_H * 2);
  int*            bsum    = (int*)alloc(64 * 4);
  float*          outp    = (float*)d_out;

  const int B = 256;
  const int nscan = (N + 1023) / 1024;        // 49

  k_init      <<<(F_H * F_IN + F_OP * F_H + B - 1) / B, B, 0, stream>>>(W1, W2, W1t, W2t, cnt, N);
  k_count     <<<(E + B - 1) / B, B, 0, stream>>>(dst, cnt, E);
  k_scan_local<<<nscan, 1024, 0, stream>>>(cnt, row_ptr, bsum, N);
  k_scan_add  <<<(N + 1 + B - 1) / B, B, 0, stream>>>(row_ptr, bsum, cnt, cursor, dinv, N, E, nscan);
  k_scatter   <<<(E + B - 1) / B, B, 0, stream>>>(src, dst, cursor, src_sorted, E);
  k_gemm1     <<<(N + 63) / 64, B, 0, stream>>>(x, W1t, h1, N);
  {
    long long threads = (long long)N * 16;
    k_agg1<<<(int)((threads + B - 1) / B), B, 0, stream>>>(h1, dinv, row_ptr, src_sorted, b1, a1b, N);
  }
  k_gemm2<<<(N + 127) / 128, 256, 0, stream>>>(a1b, W2t, h2, N);
  {
    long long threads = (long long)N * 8;
    k_agg2sm<<<(int)((threads + B - 1) / B), B, 0, stream>>>(h2, dinv, row_ptr, src_sorted, b2, outp, N);
  }
}

// Round 13
// 148.349 us; speedup vs baseline: 1.2037x; 1.2037x over previous
//
#include <hip/hip_runtime.h>
#include <hip/hip_bf16.h>
#include <hip/hip_fp8.h>
#include <cstddef>
#include <cstdint>

typedef __attribute__((ext_vector_type(8))) short short8;
typedef __attribute__((ext_vector_type(4))) float f32x4;
typedef __attribute__((ext_vector_type(2))) float f32x2;

static constexpr int F_IN  = 512;
static constexpr int F_H   = 128;
static constexpr int F_OUT = 40;
static constexpr int F_OP  = 48;
static constexpr int H2B   = 48;

__device__ inline unsigned short f2bf(float f) {
  return __builtin_bit_cast(unsigned short, __float2bfloat16(f));
}
__device__ inline void gload_lds16(const void* g, void* l) {
  __builtin_amdgcn_global_load_lds(
      (const __attribute__((address_space(1))) void*)g,
      (__attribute__((address_space(3))) void*)l, 16, 0, 0);
}

// ---------------- fp8 e4m3 (OCP on gfx950) helpers ----------------
#if __has_builtin(__builtin_amdgcn_cvt_pk_fp8_f32) && __has_builtin(__builtin_amdgcn_cvt_pk_f32_fp8)
#define FP8_HW 1
#else
#define FP8_HW 0
#endif

__device__ inline uint32_t f2fp8x2(float a, float b) {
#if FP8_HW
  return (uint32_t)__builtin_amdgcn_cvt_pk_fp8_f32(a, b, 0, false) & 0xFFFFu;
#else
  __hip_fp8_e4m3 ta(a), tb(b);
  return (uint32_t)ta.__x | ((uint32_t)tb.__x << 8);
#endif
}

__device__ inline void fp8x8_to_f32(uint2 u, float* o) {
#if FP8_HW
  f32x2 p0 = __builtin_amdgcn_cvt_pk_f32_fp8(u.x, false);
  f32x2 p1 = __builtin_amdgcn_cvt_pk_f32_fp8(u.x, true);
  f32x2 p2 = __builtin_amdgcn_cvt_pk_f32_fp8(u.y, false);
  f32x2 p3 = __builtin_amdgcn_cvt_pk_f32_fp8(u.y, true);
  o[0] = p0[0]; o[1] = p0[1]; o[2] = p1[0]; o[3] = p1[1];
  o[4] = p2[0]; o[5] = p2[1]; o[6] = p3[0]; o[7] = p3[1];
#else
  uint32_t w[2] = {u.x, u.y};
#pragma unroll
  for (int i = 0; i < 8; ++i) {
    __hip_fp8_e4m3 t; t.__x = (uint8_t)((w[i >> 2] >> ((i & 3) * 8)) & 0xFF);
    o[i] = (float)t;
  }
#endif
}

// ---------------- K1: zero cnt + convert W1/W2 ----------------
__global__ void k_init(const float* __restrict__ W1, const float* __restrict__ W2,
                       unsigned short* __restrict__ W1t, unsigned short* __restrict__ W2t,
                       int* __restrict__ cnt, int N) {
  int i = blockIdx.x * blockDim.x + threadIdx.x;
  if (i < F_H * F_IN) {
    int f = i >> 9, k = i & 511;
    W1t[i] = f2bf(W1[(size_t)k * F_H + f]);
  } else {
    int j = i - F_H * F_IN;
    if (j < F_OP * F_H) {
      int c = j >> 7, k = j & 127;
      float v = (c < F_OUT) ? W2[(size_t)k * F_OUT + c] : 0.f;
      W2t[j] = f2bf(v);
    }
  }
  if (i < N) cnt[i] = 0;
}

// ---------------- K2: degree count ----------------
__global__ void k_count(const int* __restrict__ dst, int* __restrict__ cnt, int E) {
  int e = blockIdx.x * blockDim.x + threadIdx.x;
  if (e < E) atomicAdd(&cnt[dst[e]], 1);
}

// ---------------- K3: per-block scan ----------------
__global__ void k_scan_local(const int* __restrict__ cnt, int* __restrict__ rp,
                             int* __restrict__ bsum, int N) {
  __shared__ int tmp[1024];
  int t = threadIdx.x;
  int i = blockIdx.x * 1024 + t;
  int v = (i < N) ? cnt[i] : 0;
  tmp[t] = v;
  __syncthreads();
  for (int off = 1; off < 1024; off <<= 1) {
    int u = (t >= off) ? tmp[t - off] : 0;
    __syncthreads();
    tmp[t] += u;
    __syncthreads();
  }
  if (i < N) rp[i] = tmp[t] - v;
  if (t == 1023) bsum[blockIdx.x] = tmp[1023];
}

// ---------------- K4: finalize row_ptr, seed cursor, dinv ----------------
__global__ void k_scan_add(int* __restrict__ rp, const int* __restrict__ bsum,
                           const int* __restrict__ cnt, int* __restrict__ cursor,
                           float* __restrict__ dinv, int N, int E, int nb) {
  __shared__ int sb[64];
  int t = threadIdx.x;
  if (t < 64) {
    int v = (t < nb) ? bsum[t] : 0;
    int orig = v;
#pragma unroll
    for (int off = 1; off < 64; off <<= 1) {
      int u = __shfl_up(v, off);
      if ((t & 63) >= off) v += u;
    }
    sb[t] = v - orig;
  }
  __syncthreads();
  int i = blockIdx.x * blockDim.x + t;
  if (i < N) {
    int r = rp[i] + sb[i >> 10];
    rp[i] = r;
    cursor[i] = r;
    dinv[i] = rsqrtf((float)cnt[i] + 1.0f);
  }
  if (i == N) rp[N] = E;
}

// ---------------- K5: [gemm1 blocks | scatter blocks] ----------------------
// gemm1: BM=64, BN=128, BK=64; A direct-from-global, B via global_load_lds
// into XOR-swizzled double-buffered LDS. Epilogue folds dinv[row] and stores
// h1' = (x@W1)*dinv as fp8 [N][128].
// scatter: counting-sort edges by dst into ushort src_sorted (N < 65536).
__global__ __launch_bounds__(256) void k_g1sc(const float* __restrict__ x,
                                              const unsigned short* __restrict__ Wt,
                                              const float* __restrict__ dinv,
                                              unsigned char* __restrict__ h, int N,
                                              const int* __restrict__ src,
                                              const int* __restrict__ dst,
                                              int* __restrict__ cursor,
                                              unsigned short* __restrict__ src_sorted, int E,
                                              int ngemm) {
  __shared__ unsigned short Bt[2][128][64];   // 32 KB
  const int bid = blockIdx.x;
  if (bid >= ngemm) {
    int e = (bid - ngemm) * 256 + threadIdx.x;
    if (e < E) {
      int d = dst[e];
      int pos = atomicAdd(&cursor[d], 1);
      src_sorted[pos] = (unsigned short)src[e];
    }
    return;
  }

  const int t = threadIdx.x, lane = t & 63, w = t >> 6;
  const int l16 = lane & 15, g = lane >> 4;
  const int row0 = bid * 64;

  int bsrow[4], bslc[4];
#pragma unroll
  for (int r = 0; r < 4; ++r) {
    int rg = r * 32 + w * 8;
    bsrow[r] = rg + (lane >> 3);
    bslc[r]  = (lane & 7) ^ (bsrow[r] & 7);
  }

  int ar = row0 + w * 16 + l16; if (ar >= N) ar = N - 1;
  const float* ap = x + (size_t)ar * F_IN + g * 8;

  f32x4 acc[8];
#pragma unroll
  for (int j = 0; j < 8; ++j) acc[j] = (f32x4){0.f, 0.f, 0.f, 0.f};

  auto issueB = [&](int buf, int k0) {
#pragma unroll
    for (int r = 0; r < 4; ++r)
      gload_lds16(Wt + (size_t)bsrow[r] * F_IN + k0 + bslc[r] * 8,
                  &Bt[buf][r * 32 + w * 8][0]);
  };

  issueB(0, 0);
  __syncthreads();

  for (int kt = 0; kt < 8; ++kt) {
    const int cur = kt & 1;
    if (kt < 7) issueB(cur ^ 1, (kt + 1) * 64);

    short8 af[2];
#pragma unroll
    for (int ks = 0; ks < 2; ++ks) {
      const float* p = ap + kt * 64 + ks * 32;
      float4 lo = *(const float4*)p;
      float4 hi = *(const float4*)(p + 4);
      short8 v;
      v[0] = (short)f2bf(lo.x); v[1] = (short)f2bf(lo.y);
      v[2] = (short)f2bf(lo.z); v[3] = (short)f2bf(lo.w);
      v[4] = (short)f2bf(hi.x); v[5] = (short)f2bf(hi.y);
      v[6] = (short)f2bf(hi.z); v[7] = (short)f2bf(hi.w);
      af[ks] = v;
    }

#pragma unroll
    for (int ks = 0; ks < 2; ++ks) {
      const int lcf = ks * 4 + g;
      short8 bfr[8];
#pragma unroll
      for (int fc = 0; fc < 8; ++fc) {
        int rr = fc * 16 + l16;
        bfr[fc] = *(const short8*)&Bt[cur][rr][(lcf ^ (rr & 7)) * 8];
      }
#pragma unroll
      for (int fc = 0; fc < 8; ++fc)
        acc[fc] = __builtin_amdgcn_mfma_f32_16x16x32_bf16(af[ks], bfr[fc], acc[fc], 0, 0, 0);
    }
    __syncthreads();
  }

  // epilogue: scale by dinv[row], pack fp8
  int rbase = row0 + w * 16 + g * 4;            // multiple of 4, < Npad
  float4 dv = *(const float4*)(dinv + rbase);
  float dvv[4] = {dv.x, dv.y, dv.z, dv.w};
#pragma unroll
  for (int fc = 0; fc < 8; ++fc) {
    int col = fc * 16 + l16;
#pragma unroll
    for (int jp = 0; jp < 2; ++jp) {
      uint32_t pk = f2fp8x2(acc[fc][jp * 2] * dvv[jp * 2],
                            acc[fc][jp * 2 + 1] * dvv[jp * 2 + 1]);
      int r0 = rbase + jp * 2;
      if (r0 < N)     h[(size_t)r0 * F_H + col]       = (unsigned char)(pk & 0xFF);
      if (r0 + 1 < N) h[(size_t)(r0 + 1) * F_H + col] = (unsigned char)(pk >> 8);
    }
  }
}

// ---------------- K6: agg1 (fp8 gather, dinv pre-folded) -------------------
// a1[n] = ReLU(dinv[n] * (h'[n] + sum_s h'[s]) + b1), h' already * dinv[src].
__global__ void k_agg1(const unsigned char* __restrict__ h, const float* __restrict__ dinv,
                       const int* __restrict__ rp, const unsigned short* __restrict__ srcs,
                       const float* __restrict__ bias, unsigned short* __restrict__ out, int N) {
  int gid = blockIdx.x * blockDim.x + threadIdx.x;
  int n = gid >> 4;
  if (n >= N) return;
  const int lane = threadIdx.x & 63;
  const int l16 = lane & 15;
  const int gbase = lane & 48;
  const int f = l16 * 8;

  float acc[8], tmp[8];
  uint2 sv = *(const uint2*)(h + (size_t)n * F_H + f);
  fp8x8_to_f32(sv, acc);   // self term (already * dinv[n])

  int beg = rp[n], end = rp[n + 1];
  for (int jb = beg; jb < end; jb += 16) {
    int lim = end - jb; if (lim > 16) lim = 16;
    int sidx = srcs[jb + ((l16 < lim) ? l16 : 0)];

    if (lim == 16) {
#pragma unroll
      for (int i = 0; i < 16; ++i) {
        int s = __shfl(sidx, gbase + i);
        uint2 hv = *(const uint2*)(h + (size_t)s * F_H + f);
        fp8x8_to_f32(hv, tmp);
#pragma unroll
        for (int q = 0; q < 8; ++q) acc[q] += tmp[q];
      }
    } else {
      for (int i = 0; i < lim; ++i) {
        int s = __shfl(sidx, gbase + i);
        uint2 hv = *(const uint2*)(h + (size_t)s * F_H + f);
        fp8x8_to_f32(hv, tmp);
#pragma unroll
        for (int q = 0; q < 8; ++q) acc[q] += tmp[q];
      }
    }
  }

  float dn = dinv[n];
#pragma unroll
  for (int i = 0; i < 8; ++i) {
    acc[i] = acc[i] * dn + bias[f + i];
    acc[i] = fmaxf(acc[i], 0.f);
  }
  uint4 o;
  o.x = f2bf(acc[0]) | ((unsigned)f2bf(acc[1]) << 16);
  o.y = f2bf(acc[2]) | ((unsigned)f2bf(acc[3]) << 16);
  o.z = f2bf(acc[4]) | ((unsigned)f2bf(acc[5]) << 16);
  o.w = f2bf(acc[6]) | ((unsigned)f2bf(acc[7]) << 16);
  *(uint4*)(out + (size_t)n * F_H + f) = o;
}

// ---------------- K7: GEMM2 (MFMA bf16) -> h2' = (a1@W2)*dinv, fp8 ---------
__global__ __launch_bounds__(256) void k_gemm2(const unsigned short* __restrict__ a,
                                               const unsigned short* __restrict__ W2t,
                                               const float* __restrict__ dinv,
                                               unsigned char* __restrict__ h2, int N) {
  const int t = threadIdx.x, lane = t & 63, w = t >> 6;
  const int l16 = lane & 15, g = lane >> 4;
  const int row0 = blockIdx.x * 128 + w * 32;

  short8 bfr[3][4];
#pragma unroll
  for (int fc = 0; fc < 3; ++fc)
#pragma unroll
    for (int ks = 0; ks < 4; ++ks)
      bfr[fc][ks] = *(const short8*)(W2t + (size_t)(fc * 16 + l16) * F_H + ks * 32 + g * 8);

  f32x4 acc[2][3];
#pragma unroll
  for (int i = 0; i < 2; ++i)
#pragma unroll
    for (int j = 0; j < 3; ++j) acc[i][j] = (f32x4){0.f, 0.f, 0.f, 0.f};

  short8 af[2][4];
#pragma unroll
  for (int fr = 0; fr < 2; ++fr) {
    int r = row0 + fr * 16 + l16; if (r >= N) r = N - 1;
#pragma unroll
    for (int ks = 0; ks < 4; ++ks)
      af[fr][ks] = *(const short8*)(a + (size_t)r * F_H + ks * 32 + g * 8);
  }

#pragma unroll
  for (int fr = 0; fr < 2; ++fr)
#pragma unroll
    for (int ks = 0; ks < 4; ++ks)
#pragma unroll
      for (int fc = 0; fc < 3; ++fc)
        acc[fr][fc] = __builtin_amdgcn_mfma_f32_16x16x32_bf16(af[fr][ks], bfr[fc][ks], acc[fr][fc], 0, 0, 0);

#pragma unroll
  for (int fr = 0; fr < 2; ++fr) {
    int rbase = row0 + fr * 16 + g * 4;   // multiple of 4, < Npad
    float4 dv = *(const float4*)(dinv + rbase);
    float dvv[4] = {dv.x, dv.y, dv.z, dv.w};
#pragma unroll
    for (int fc = 0; fc < 3; ++fc) {
      int col = fc * 16 + l16;
#pragma unroll
      for (int jp = 0; jp < 2; ++jp) {
        uint32_t pk = f2fp8x2(acc[fr][fc][jp * 2] * dvv[jp * 2],
                              acc[fr][fc][jp * 2 + 1] * dvv[jp * 2 + 1]);
        int r0 = rbase + jp * 2;
        if (r0 < N)     h2[(size_t)r0 * H2B + col]       = (unsigned char)(pk & 0xFF);
        if (r0 + 1 < N) h2[(size_t)(r0 + 1) * H2B + col] = (unsigned char)(pk >> 8);
      }
    }
  }
}

// ---------------- K8: layer-2 agg (dinv pre-folded) + b2 + log_softmax -----
__global__ void k_agg2sm(const unsigned char* __restrict__ h2, const float* __restrict__ dinv,
                         const int* __restrict__ rp, const unsigned short* __restrict__ srcs,
                         const float* __restrict__ b2, float* __restrict__ out, int N) {
  int gid = blockIdx.x * blockDim.x + threadIdx.x;
  int n = gid >> 3;
  if (n >= N) return;
  const int lane = threadIdx.x & 63;
  const int l8 = lane & 7;
  const int gb = lane & 56;
  const int f = l8 * 8;
  const bool live = (l8 < 5);

  float acc[8], tmp[8];
#pragma unroll
  for (int i = 0; i < 8; ++i) acc[i] = 0.f;
  if (live) {
    uint2 sv = *(const uint2*)(h2 + (size_t)n * H2B + f);
    fp8x8_to_f32(sv, acc);   // self term
  }

  int beg = rp[n], end = rp[n + 1];
  for (int jb = beg; jb < end; jb += 8) {
    int lim = end - jb; if (lim > 8) lim = 8;
    int sidx = srcs[jb + ((l8 < lim) ? l8 : 0)];

    for (int i = 0; i < lim; ++i) {
      int s = __shfl(sidx, gb + i);
      if (live) {
        uint2 hv = *(const uint2*)(h2 + (size_t)s * H2B + f);
        fp8x8_to_f32(hv, tmp);
#pragma unroll
        for (int q = 0; q < 8; ++q) acc[q] += tmp[q];
      }
    }
  }

  float dn = dinv[n];
  float vals[8];
  float m = -3.0e38f;
#pragma unroll
  for (int q = 0; q < 8; ++q) {
    int col = f + q;
    if (col < F_OUT) {
      vals[q] = acc[q] * dn + b2[col];
      m = fmaxf(m, vals[q]);
    } else {
      vals[q] = -3.0e38f;
    }
  }
#pragma unroll
  for (int off = 4; off > 0; off >>= 1) m = fmaxf(m, __shfl_xor(m, off));
  float e = 0.f;
#pragma unroll
  for (int q = 0; q < 8; ++q) {
    int col = f + q;
    if (col < F_OUT) e += expf(vals[q] - m);
  }
#pragma unroll
  for (int off = 4; off > 0; off >>= 1) e += __shfl_xor(e, off);
  float ls = logf(e) + m;

  if (live) {
    float4 o0 = {vals[0] - ls, vals[1] - ls, vals[2] - ls, vals[3] - ls};
    float4 o1 = {vals[4] - ls, vals[5] - ls, vals[6] - ls, vals[7] - ls};
    float* op = out + (size_t)n * F_OUT + f;
    *(float4*)op = o0;
    *(float4*)(op + 4) = o1;
  }
}

extern "C" void kernel_launch(void* const* d_in, const int* in_sizes, int n_in,
                              void* d_out, int out_size, void* d_ws, size_t ws_size,
                              hipStream_t stream) {
  const float* x  = (const float*)d_in[0];
  const int*   ei = (const int*)d_in[1];
  const float* W1 = (const float*)d_in[2];
  const float* b1 = (const float*)d_in[3];
  const float* W2 = (const float*)d_in[4];
  const float* b2 = (const float*)d_in[5];

  const int N = in_sizes[0] / F_IN;   // 50000 (< 65536: ushort indices OK)
  const int E = in_sizes[1] / 2;      // 800000
  const int* src = ei;
  const int* dst = ei + E;

  // workspace layout (byte-addressed, 256B-aligned chunks)
  char* base = (char*)d_ws;
  auto alloc = [&](size_t bytes) {
    char* p = base;
    base += (bytes + 255) & ~(size_t)255;
    return p;
  };
  size_t Npad = ((size_t)N + 1023) & ~(size_t)1023;
  float*          dinv    = (float*)alloc(Npad * 4);
  unsigned char*  h1      = (unsigned char*)alloc((size_t)N * F_H);        // fp8
  unsigned short* a1b     = (unsigned short*)alloc((size_t)N * F_H * 2);   // bf16
  unsigned char*  h2      = (unsigned char*)alloc((size_t)N * H2B);        // fp8
  int*            cnt     = (int*)alloc(Npad * 4);
  int*            row_ptr = (int*)alloc((Npad + 64) * 4);
  int*            cursor  = (int*)alloc(Npad * 4);
  unsigned short* src_sorted = (unsigned short*)alloc((size_t)E * 2);
  unsigned short* W1t     = (unsigned short*)alloc((size_t)F_H * F_IN * 2);
  unsigned short* W2t     = (unsigned short*)alloc((size_t)F_OP * F_H * 2);
  int*            bsum    = (int*)alloc(64 * 4);
  float*          outp    = (float*)d_out;

  const int B = 256;
  const int nscan = (N + 1023) / 1024;        // 49
  const int ngemm = (N + 63) / 64;            // 782
  const int nscat = (E + B - 1) / B;          // 3125

  k_init      <<<(F_H * F_IN + F_OP * F_H + B - 1) / B, B, 0, stream>>>(W1, W2, W1t, W2t, cnt, N);
  k_count     <<<(E + B - 1) / B, B, 0, stream>>>(dst, cnt, E);
  k_scan_local<<<nscan, 1024, 0, stream>>>(cnt, row_ptr, bsum, N);
  k_scan_add  <<<(N + 1 + B - 1) / B, B, 0, stream>>>(row_ptr, bsum, cnt, cursor, dinv, N, E, nscan);
  k_g1sc      <<<ngemm + nscat, B, 0, stream>>>(x, W1t, dinv, h1, N, src, dst, cursor, src_sorted, E, ngemm);
  {
    long long threads = (long long)N * 16;
    k_agg1<<<(int)((threads + B - 1) / B), B, 0, stream>>>(h1, dinv, row_ptr, src_sorted, b1, a1b, N);
  }
  k_gemm2<<<(N + 127) / 128, 256, 0, stream>>>(a1b, W2t, dinv, h2, N);
  {
    long long threads = (long long)N * 8;
    k_agg2sm<<<(int)((threads + B - 1) / B), B, 0, stream>>>(h2, dinv, row_ptr, src_sorted, b2, outp, N);
  }
}